// Round 12
// baseline (161.924 us; speedup 1.0000x reference)
//
#include <hip/hip_runtime.h>
#include <hip/hip_bf16.h>

using bf16 = __hip_bfloat16;

typedef __attribute__((ext_vector_type(8))) __bf16 bf16x8;
typedef __attribute__((ext_vector_type(4))) float f32x4;

#define NPTS 4096
#define DMODEL 512
#define HDIM 64
#define KNN 9
#define MROWS 8192  // B*N

#define GRIDW 32
#define CELLW 3.125f   // 100/32, exact in f32
#define NCELL (GRIDW * GRIDW)

// ---------------- workspace layout (all sizes bytes) ----------------
#define NN_BYTES    (MROWS * 16 * 4)             // 512 KB
#define QKV_BYTES   ((size_t)MROWS * 1536 * 2)   // 25.2 MB
#define G_BYTES     ((size_t)MROWS * 512 * 2)    // 8.4 MB
#define XB_BYTES    ((size_t)MROWS * 512 * 2)    // 8.4 MB
#define WQ_BYTES    ((size_t)1536 * 512 * 2)     // 1.5 MB
#define WP_BYTES    ((size_t)512 * 512 * 2)      // 0.5 MB
#define GSTART_BYTES (2 * 1025 * 4)
#define SXY_BYTES    ((size_t)2 * NPTS * 8)
#define SIDX_BYTES   ((size_t)2 * NPTS * 4)

// ---------------- prep: cvt (blocks 0..1279) + grid_build (blocks 1280..1281) --
// cvt: f32 -> bf16 for x, w_qkv, w_proj (1310720 float4 = 1280 x 1024 exactly).
// grid_build: counting-sort points by 32x32 cell; order within cell arbitrary.
__global__ __launch_bounds__(1024) void prep_kernel(
    const float4* __restrict__ s0, ushort4* __restrict__ d0, int n0,
    const float4* __restrict__ s1, ushort4* __restrict__ d1, int n1,
    const float4* __restrict__ s2, ushort4* __restrict__ d2, int n2,
    const float* __restrict__ coords,
    int* __restrict__ gstart,   // [2][1025]
    float2* __restrict__ sxy,   // [2][4096]
    int* __restrict__ sidx) {   // [2][4096]
    __shared__ int cnt[NCELL];
    __shared__ int off2[NCELL];
    __shared__ int sstart[NCELL];
    __shared__ int wsum[16];

    if (blockIdx.x < 1280) {
        int g = blockIdx.x * 1024 + threadIdx.x;
        const float4* s; ushort4* d; int i;
        if (g < n0) { s = s0; d = d0; i = g; }
        else if (g < n0 + n1) { s = s1; d = d1; i = g - n0; }
        else { s = s2; d = d2; i = g - n0 - n1; }
        float4 v = s[i];
        bf16 b0 = __float2bfloat16(v.x), b1 = __float2bfloat16(v.y);
        bf16 b2 = __float2bfloat16(v.z), b3 = __float2bfloat16(v.w);
        ushort4 o;
        o.x = *reinterpret_cast<unsigned short*>(&b0);
        o.y = *reinterpret_cast<unsigned short*>(&b1);
        o.z = *reinterpret_cast<unsigned short*>(&b2);
        o.w = *reinterpret_cast<unsigned short*>(&b3);
        d[i] = o;
        return;
    }

    const int b = blockIdx.x - 1280, tid = threadIdx.x;
    cnt[tid] = 0; off2[tid] = 0;
    __syncthreads();
    const float2* c2 = (const float2*)(coords + (size_t)b * NPTS * 2);
    float px[4], py[4]; int pc[4];
#pragma unroll
    for (int i = 0; i < 4; ++i) {
        int p = tid + i * 1024;
        float2 v = c2[p];
        px[i] = v.x; py[i] = v.y;
        int cx = min(GRIDW - 1, (int)(v.x / CELLW));
        int cy = min(GRIDW - 1, (int)(v.y / CELLW));
        pc[i] = cy * GRIDW + cx;
        atomicAdd(&cnt[pc[i]], 1);
    }
    __syncthreads();
    const int v = cnt[tid];
    const int lane = tid & 63, wv = tid >> 6;
    int inc = v;
#pragma unroll
    for (int o = 1; o < 64; o <<= 1) {
        int t = __shfl_up(inc, o, 64);
        if (lane >= o) inc += t;
    }
    if (lane == 63) wsum[wv] = inc;
    __syncthreads();
    if (tid < 16) {
        int w = wsum[tid];
#pragma unroll
        for (int o = 1; o < 16; o <<= 1) {
            int t = __shfl_up(w, o, 16);
            if (tid >= o) w += t;
        }
        wsum[tid] = w;
    }
    __syncthreads();
    const int excl = inc - v + (wv ? wsum[wv - 1] : 0);
    sstart[tid] = excl;
    gstart[b * 1025 + tid] = excl;
    if (tid == 1023) gstart[b * 1025 + 1024] = excl + v;
    __syncthreads();
#pragma unroll
    for (int i = 0; i < 4; ++i) {
        int o = atomicAdd(&off2[pc[i]], 1);
        int pos = sstart[pc[i]] + o;
        sxy[(size_t)b * NPTS + pos]  = make_float2(px[i], py[i]);
        sidx[(size_t)b * NPTS + pos] = tid + i * 1024;
    }
}

// ---------------- mid: qkv GEMM (blocks 0..767) + kNN (blocks 768..2815) -----
__device__ __forceinline__ void gload16(const bf16* g, bf16* l) {
    __builtin_amdgcn_global_load_lds(
        (const __attribute__((address_space(1))) unsigned int*)g,
        (__attribute__((address_space(3))) unsigned int*)l,
        16, 0, 0);
}

__global__ __launch_bounds__(256) void mid_kernel(
    const bf16* __restrict__ A, const bf16* __restrict__ W,
    bf16* __restrict__ Cout,                       // qkv out, Nn=1536, Kd=512
    const float* __restrict__ coords, const int* __restrict__ gstart,
    const float2* __restrict__ sxy, const int* __restrict__ sidx,
    int* __restrict__ nn_out) {
    __shared__ __attribute__((aligned(16))) bf16 As[2][128][32];
    __shared__ __attribute__((aligned(16))) bf16 Bs[2][128][32];

    const int tid = threadIdx.x;
    const int lane = tid & 63;

    if (blockIdx.x < 768) {
        const int Nn = 1536, Kd = 512, nk = 16;
        const int rowBase = (blockIdx.x & 63) * 128;
        const int colBase = (blockIdx.x >> 6) * 128;
        const int w = tid >> 6;
        const int wr = w >> 1, wc = w & 1;
        const int r0  = tid >> 2;
        const int kk0 = (tid & 3) * 8;

        f32x4 acc[4][4] = {};
        const bf16* gaBase = A + (size_t)(rowBase + r0) * Kd + kk0;
        const bf16* gbBase = W + (size_t)(colBase + r0) * Kd + kk0;

#define STAGE(bufi, kt)                                                     \
        do {                                                                \
            const bf16* ga = gaBase + (size_t)(kt) * 32;                    \
            const bf16* gb = gbBase + (size_t)(kt) * 32;                    \
            gload16(ga,                   &As[bufi][r0][kk0]);              \
            gload16(ga + (size_t)64 * Kd, &As[bufi][r0 + 64][kk0]);         \
            gload16(gb,                   &Bs[bufi][r0][kk0]);              \
            gload16(gb + (size_t)64 * Kd, &Bs[bufi][r0 + 64][kk0]);         \
        } while (0)

        STAGE(0, 0);
        __syncthreads();

        int buf = 0;
        const int r16 = lane & 15;
        const int hk  = (lane >> 4) * 8;
        for (int kt = 0; kt < nk; ++kt) {
            if (kt + 1 < nk) STAGE(buf ^ 1, kt + 1);
            bf16x8 afr[4], bfr[4];
#pragma unroll
            for (int m2 = 0; m2 < 4; ++m2)
                afr[m2] = *(const bf16x8*)&As[buf][wr * 64 + m2 * 16 + r16][hk];
#pragma unroll
            for (int n2 = 0; n2 < 4; ++n2)
                bfr[n2] = *(const bf16x8*)&Bs[buf][wc * 64 + n2 * 16 + r16][hk];
#pragma unroll
            for (int m2 = 0; m2 < 4; ++m2)
#pragma unroll
                for (int n2 = 0; n2 < 4; ++n2)
                    acc[m2][n2] = __builtin_amdgcn_mfma_f32_16x16x32_bf16(
                        afr[m2], bfr[n2], acc[m2][n2], 0, 0, 0);
            __syncthreads();
            buf ^= 1;
        }
#undef STAGE

        const int r4  = (lane >> 4) * 4;
        const int c16 = lane & 15;
#pragma unroll
        for (int m2 = 0; m2 < 4; ++m2) {
#pragma unroll
            for (int n2 = 0; n2 < 4; ++n2) {
                const int gc = colBase + wc * 64 + n2 * 16 + c16;
#pragma unroll
                for (int r = 0; r < 4; ++r) {
                    const int gr = rowBase + wr * 64 + m2 * 16 + r4 + r;
                    Cout[(size_t)gr * Nn + gc] = __float2bfloat16(acc[m2][n2][r]);
                }
            }
        }
        return;
    }

    // ---- kNN branch ----
    const int wv = tid >> 6;
    const int q = (blockIdx.x - 768) * 4 + wv;  // 0..8191
    const int b = q >> 12, n = q & 4095;
    const float2* cb = (const float2*)(coords + (size_t)b * NPTS * 2);
    const float2 pq = cb[n];
    const float xn = pq.x, yn = pq.y;
    const float sn = __fadd_rn(__fmul_rn(xn, xn), __fmul_rn(yn, yn));
    const int cx = min(GRIDW - 1, (int)(xn / CELLW));
    const int cy = min(GRIDW - 1, (int)(yn / CELLW));
    const int* gs = gstart + b * 1025;
    const float2* xy = sxy + (size_t)b * NPTS;
    const int* id = sidx + (size_t)b * NPTS;

    float d9 = 0.0f;
    int outi[9];
    for (int r = 2;; ++r) {
        float bd[10]; int bi[10];
#pragma unroll
        for (int j = 0; j < 10; ++j) { bd[j] = 3.4e38f; bi[j] = 0x7fffffff; }
        const int ylo = max(cy - r, 0), yhi = min(cy + r, GRIDW - 1);
        const int xlo = max(cx - r, 0), xhi = min(cx + r, GRIDW - 1);
        for (int ry = ylo; ry <= yhi; ++ry) {
            const int s0 = gs[ry * GRIDW + xlo];
            const int s1 = gs[ry * GRIDW + xhi + 1];
            for (int p0 = s0; p0 < s1; p0 += 64) {
                const int pp = p0 + lane;
                float d = 3.4e38f; int idx = 0x7fffffff;
                if (pp < s1) {
                    float2 cm = xy[pp];
                    idx = id[pp];
                    float sc  = __fadd_rn(__fmul_rn(cm.x, cm.x), __fmul_rn(cm.y, cm.y));
                    float dot = __fadd_rn(__fmul_rn(xn, cm.x), __fmul_rn(yn, cm.y));
                    float d2  = __fsub_rn(__fadd_rn(sn, sc), __fmul_rn(2.0f, dot));
                    d = sqrtf(fmaxf(d2, 0.0f));
                }
                if (d < bd[8]) {
#pragma unroll
                    for (int j = 8; j >= 1; --j) {
                        if (d < bd[j]) {
                            bool t2 = d < bd[j - 1];
                            bd[j] = t2 ? bd[j - 1] : d;
                            bi[j] = t2 ? bi[j - 1] : idx;
                        }
                    }
                    if (d < bd[0]) { bd[0] = d; bi[0] = idx; }
                }
            }
        }
        unsigned long long head =
            ((unsigned long long)__float_as_uint(bd[0]) << 32) | (unsigned)bi[0];
#pragma unroll
        for (int rr = 0; rr < 9; ++rr) {
            unsigned long long m = head;
#pragma unroll
            for (int s2 = 32; s2 > 0; s2 >>= 1) {
                unsigned long long o = __shfl_xor(m, s2, 64);
                m = o < m ? o : m;
            }
            outi[rr] = (int)(unsigned)(m & 0xffffffffULL);
            if (rr == 8) d9 = __uint_as_float((unsigned)(m >> 32));
            if (m == head) {
#pragma unroll
                for (int j = 0; j < 9; ++j) { bd[j] = bd[j + 1]; bi[j] = bi[j + 1]; }
                head = ((unsigned long long)__float_as_uint(bd[0]) << 32) | (unsigned)bi[0];
            }
        }
        if (d9 <= (float)r * CELLW - 0.01f || r >= 34) break;
    }
    if (lane == 0) {
        int* o = nn_out + (size_t)q * 16;
#pragma unroll
        for (int rr = 0; rr < 9; ++rr) o[rr] = outi[rr];
    }
}

// ---------------- proj GEMM with bias+residual epilogue (f32 out) ----------------
__global__ __launch_bounds__(256) void gemm_epi(const bf16* __restrict__ A,
                                                const bf16* __restrict__ W,
                                                float* __restrict__ Cout,
                                                const float* __restrict__ bias,
                                                const float* __restrict__ resid) {
    __shared__ __attribute__((aligned(16))) bf16 As[2][128][32];
    __shared__ __attribute__((aligned(16))) bf16 Bs[2][128][32];

    const int Nn = 512, Kd = 512, nk = 16;
    const int tid = threadIdx.x;
    const int rowBase = blockIdx.x * 128;
    const int colBase = blockIdx.y * 128;
    const int lane = tid & 63, w = tid >> 6;
    const int wr = w >> 1, wc = w & 1;
    const int r0  = tid >> 2;
    const int kk0 = (tid & 3) * 8;

    f32x4 acc[4][4] = {};
    const bf16* gaBase = A + (size_t)(rowBase + r0) * Kd + kk0;
    const bf16* gbBase = W + (size_t)(colBase + r0) * Kd + kk0;

#define STAGE(bufi, kt)                                                     \
    do {                                                                    \
        const bf16* ga = gaBase + (size_t)(kt) * 32;                        \
        const bf16* gb = gbBase + (size_t)(kt) * 32;                        \
        gload16(ga,                   &As[bufi][r0][kk0]);                  \
        gload16(ga + (size_t)64 * Kd, &As[bufi][r0 + 64][kk0]);             \
        gload16(gb,                   &Bs[bufi][r0][kk0]);                  \
        gload16(gb + (size_t)64 * Kd, &Bs[bufi][r0 + 64][kk0]);             \
    } while (0)

    STAGE(0, 0);
    __syncthreads();

    int buf = 0;
    const int r16 = lane & 15;
    const int hk  = (lane >> 4) * 8;
    for (int kt = 0; kt < nk; ++kt) {
        if (kt + 1 < nk) STAGE(buf ^ 1, kt + 1);
        bf16x8 afr[4], bfr[4];
#pragma unroll
        for (int m2 = 0; m2 < 4; ++m2)
            afr[m2] = *(const bf16x8*)&As[buf][wr * 64 + m2 * 16 + r16][hk];
#pragma unroll
        for (int n2 = 0; n2 < 4; ++n2)
            bfr[n2] = *(const bf16x8*)&Bs[buf][wc * 64 + n2 * 16 + r16][hk];
#pragma unroll
        for (int m2 = 0; m2 < 4; ++m2)
#pragma unroll
            for (int n2 = 0; n2 < 4; ++n2)
                acc[m2][n2] = __builtin_amdgcn_mfma_f32_16x16x32_bf16(
                    afr[m2], bfr[n2], acc[m2][n2], 0, 0, 0);
        __syncthreads();
        buf ^= 1;
    }
#undef STAGE

    const int r4  = (lane >> 4) * 4;
    const int c16 = lane & 15;
#pragma unroll
    for (int m2 = 0; m2 < 4; ++m2) {
#pragma unroll
        for (int n2 = 0; n2 < 4; ++n2) {
            const int gc = colBase + wc * 64 + n2 * 16 + c16;
#pragma unroll
            for (int r = 0; r < 4; ++r) {
                const int gr = rowBase + wr * 64 + m2 * 16 + r4 + r;
                float v = acc[m2][n2][r] + bias[gc];
                v = resid[(size_t)gr * Nn + gc] + v;
                Cout[(size_t)gr * Nn + gc] = v;
            }
        }
    }
}

// ---------------- attention + GELU: one wave per query, all 8 heads ----------------
__global__ __launch_bounds__(256) void attn_kernel(const bf16* __restrict__ qkv,
                                                   const int* __restrict__ nn,
                                                   bf16* __restrict__ g) {
    const int wv = threadIdx.x >> 6, lane = threadIdx.x & 63;
    const int q = blockIdx.x * 4 + wv;   // 0..8191
    const int b = q >> 12;
    const int rowbase = b * NPTS;

    const int* nnq = nn + (size_t)q * 16;
    int idxs[KNN];
#pragma unroll
    for (int j = 0; j < KNN; ++j) idxs[j] = nnq[j];

    bf16x8 qv = *(const bf16x8*)(qkv + (size_t)q * 1536 + lane * 8);
    float qf[8];
#pragma unroll
    for (int e = 0; e < 8; ++e) qf[e] = (float)qv[e];

    float lg[KNN];
#pragma unroll
    for (int j = 0; j < KNN; ++j) {
        const bf16x8 kv = *(const bf16x8*)(
            qkv + (size_t)(rowbase + idxs[j]) * 1536 + DMODEL + lane * 8);
        float p = 0.0f;
#pragma unroll
        for (int e = 0; e < 8; ++e) p += qf[e] * (float)kv[e];
        p += __shfl_xor(p, 1, 64);
        p += __shfl_xor(p, 2, 64);
        p += __shfl_xor(p, 4, 64);
        lg[j] = p * 0.125f;  // / sqrt(64)
    }
    float mx = lg[0];
#pragma unroll
    for (int j = 1; j < KNN; ++j) mx = fmaxf(mx, lg[j]);
    float wgt[KNN], ssum = 0.0f;
#pragma unroll
    for (int j = 0; j < KNN; ++j) { wgt[j] = expf(lg[j] - mx); ssum += wgt[j]; }
    const float inv = 1.0f / ssum;

    float o[8] = {};
#pragma unroll
    for (int j = 0; j < KNN; ++j) {
        const bf16x8 vv = *(const bf16x8*)(
            qkv + (size_t)(rowbase + idxs[j]) * 1536 + 2 * DMODEL + lane * 8);
        const float wj = wgt[j] * inv;
#pragma unroll
        for (int e = 0; e < 8; ++e) o[e] += wj * (float)vv[e];
    }
    bf16x8 ov;
#pragma unroll
    for (int e = 0; e < 8; ++e) {
        float ge = 0.5f * o[e] * (1.0f + erff(o[e] * 0.70710678118654752f));
        ov[e] = (__bf16)__float2bfloat16(ge);
    }
    *(bf16x8*)(g + (size_t)q * DMODEL + lane * 8) = ov;
}

// ---------------- launch ----------------
extern "C" void kernel_launch(void* const* d_in, const int* in_sizes, int n_in,
                              void* d_out, int out_size, void* d_ws, size_t ws_size,
                              hipStream_t stream) {
    const float* x      = (const float*)d_in[0];
    const float* coords = (const float*)d_in[1];
    const float* w_qkv  = (const float*)d_in[2];
    const float* w_proj = (const float*)d_in[3];
    const float* b_proj = (const float*)d_in[4];
    float* out = (float*)d_out;

    char* wsb = (char*)d_ws;
    size_t off = 0;
    int*    nn     = (int*)(wsb + off);    off += NN_BYTES;
    bf16*   qkv    = (bf16*)(wsb + off);   off += QKV_BYTES;
    bf16*   g      = (bf16*)(wsb + off);   off += G_BYTES;
    bf16*   xb     = (bf16*)(wsb + off);   off += XB_BYTES;
    bf16*   wqb    = (bf16*)(wsb + off);   off += WQ_BYTES;
    bf16*   wpb    = (bf16*)(wsb + off);   off += WP_BYTES;
    int*    gstart = (int*)(wsb + off);    off += GSTART_BYTES;
    float2* sxy    = (float2*)(wsb + off); off += SXY_BYTES;
    int*    sidx   = (int*)(wsb + off);    off += SIDX_BYTES;

    // f32 -> bf16 converts: x (4194304), w_qkv (786432), w_proj (262144)
    const int n0 = 4194304 / 4, n1 = 786432 / 4, n2 = 262144 / 4;
    // total = 1310720 = 1280 * 1024; +2 grid_build blocks
    prep_kernel<<<1282, 1024, 0, stream>>>(
        (const float4*)x, (ushort4*)xb, n0,
        (const float4*)w_qkv, (ushort4*)wqb, n1,
        (const float4*)w_proj, (ushort4*)wpb, n2,
        coords, gstart, sxy, sidx);

    // qkv GEMM (768 blocks) overlapped with kNN (2048 blocks)
    mid_kernel<<<2816, 256, 0, stream>>>(xb, wqb, qkv, coords, gstart, sxy,
                                         sidx, nn);

    attn_kernel<<<2048, 256, 0, stream>>>(qkv, nn, g);
    gemm_epi<<<dim3(64, 4), 256, 0, stream>>>(g, wpb, out, b_proj, x);
}

// Round 13
// 153.530 us; speedup vs baseline: 1.0547x; 1.0547x over previous
//
#include <hip/hip_runtime.h>
#include <hip/hip_bf16.h>

using bf16 = __hip_bfloat16;

typedef __attribute__((ext_vector_type(8))) __bf16 bf16x8;
typedef __attribute__((ext_vector_type(4))) float f32x4;

#define NPTS 4096
#define DMODEL 512
#define HDIM 64
#define KNN 9
#define MROWS 8192  // B*N

#define GRIDW 32
#define CELLW 3.125f   // 100/32, exact in f32
#define NCELL (GRIDW * GRIDW)

// ---------------- workspace layout (all sizes bytes) ----------------
#define NN_BYTES    (MROWS * 16 * 4)             // 512 KB
#define QKV_BYTES   ((size_t)MROWS * 1536 * 2)   // 25.2 MB
#define G_BYTES     ((size_t)MROWS * 512 * 2)    // 8.4 MB
#define XB_BYTES    ((size_t)MROWS * 512 * 2)    // 8.4 MB
#define WQ_BYTES    ((size_t)1536 * 512 * 2)     // 1.5 MB
#define WP_BYTES    ((size_t)512 * 512 * 2)      // 0.5 MB
#define GSTART_BYTES (2 * 1025 * 4)
#define SXY_BYTES    ((size_t)2 * NPTS * 8)
#define SIDX_BYTES   ((size_t)2 * NPTS * 4)

// ---------------- prep: cvt (blocks 0..1279) + grid_build (blocks 1280..1281) --
// Verified in round 12 (absmax unchanged). cvt: f32->bf16 for x, w_qkv, w_proj.
// grid_build: counting-sort points by 32x32 cell; order within cell arbitrary.
__global__ __launch_bounds__(1024) void prep_kernel(
    const float4* __restrict__ s0, ushort4* __restrict__ d0, int n0,
    const float4* __restrict__ s1, ushort4* __restrict__ d1, int n1,
    const float4* __restrict__ s2, ushort4* __restrict__ d2, int n2,
    const float* __restrict__ coords,
    int* __restrict__ gstart,   // [2][1025]
    float2* __restrict__ sxy,   // [2][4096]
    int* __restrict__ sidx) {   // [2][4096]
    __shared__ int cnt[NCELL];
    __shared__ int off2[NCELL];
    __shared__ int sstart[NCELL];
    __shared__ int wsum[16];

    if (blockIdx.x < 1280) {
        int g = blockIdx.x * 1024 + threadIdx.x;
        const float4* s; ushort4* d; int i;
        if (g < n0) { s = s0; d = d0; i = g; }
        else if (g < n0 + n1) { s = s1; d = d1; i = g - n0; }
        else { s = s2; d = d2; i = g - n0 - n1; }
        float4 v = s[i];
        bf16 b0 = __float2bfloat16(v.x), b1 = __float2bfloat16(v.y);
        bf16 b2 = __float2bfloat16(v.z), b3 = __float2bfloat16(v.w);
        ushort4 o;
        o.x = *reinterpret_cast<unsigned short*>(&b0);
        o.y = *reinterpret_cast<unsigned short*>(&b1);
        o.z = *reinterpret_cast<unsigned short*>(&b2);
        o.w = *reinterpret_cast<unsigned short*>(&b3);
        d[i] = o;
        return;
    }

    const int b = blockIdx.x - 1280, tid = threadIdx.x;
    cnt[tid] = 0; off2[tid] = 0;
    __syncthreads();
    const float2* c2 = (const float2*)(coords + (size_t)b * NPTS * 2);
    float px[4], py[4]; int pc[4];
#pragma unroll
    for (int i = 0; i < 4; ++i) {
        int p = tid + i * 1024;
        float2 v = c2[p];
        px[i] = v.x; py[i] = v.y;
        int cx = min(GRIDW - 1, (int)(v.x / CELLW));
        int cy = min(GRIDW - 1, (int)(v.y / CELLW));
        pc[i] = cy * GRIDW + cx;
        atomicAdd(&cnt[pc[i]], 1);
    }
    __syncthreads();
    const int v = cnt[tid];
    const int lane = tid & 63, wv = tid >> 6;
    int inc = v;
#pragma unroll
    for (int o = 1; o < 64; o <<= 1) {
        int t = __shfl_up(inc, o, 64);
        if (lane >= o) inc += t;
    }
    if (lane == 63) wsum[wv] = inc;
    __syncthreads();
    if (tid < 16) {
        int w = wsum[tid];
#pragma unroll
        for (int o = 1; o < 16; o <<= 1) {
            int t = __shfl_up(w, o, 16);
            if (tid >= o) w += t;
        }
        wsum[tid] = w;
    }
    __syncthreads();
    const int excl = inc - v + (wv ? wsum[wv - 1] : 0);
    sstart[tid] = excl;
    gstart[b * 1025 + tid] = excl;
    if (tid == 1023) gstart[b * 1025 + 1024] = excl + v;
    __syncthreads();
#pragma unroll
    for (int i = 0; i < 4; ++i) {
        int o = atomicAdd(&off2[pc[i]], 1);
        int pos = sstart[pc[i]] + o;
        sxy[(size_t)b * NPTS + pos]  = make_float2(px[i], py[i]);
        sidx[(size_t)b * NPTS + pos] = tid + i * 1024;
    }
}

// ---------------- kNN via grid: one wave per query (no LDS -> high occupancy) --
__global__ __launch_bounds__(256) void knn_grid(const float* __restrict__ coords,
                                                const int* __restrict__ gstart,
                                                const float2* __restrict__ sxy,
                                                const int* __restrict__ sidx,
                                                int* __restrict__ nn_out) {
    const int wv = threadIdx.x >> 6, lane = threadIdx.x & 63;
    const int q = blockIdx.x * 4 + wv;  // 0..8191
    const int b = q >> 12, n = q & 4095;
    const float2* cb = (const float2*)(coords + (size_t)b * NPTS * 2);
    const float2 pq = cb[n];
    const float xn = pq.x, yn = pq.y;
    const float sn = __fadd_rn(__fmul_rn(xn, xn), __fmul_rn(yn, yn));
    const int cx = min(GRIDW - 1, (int)(xn / CELLW));
    const int cy = min(GRIDW - 1, (int)(yn / CELLW));
    const int* gs = gstart + b * 1025;
    const float2* xy = sxy + (size_t)b * NPTS;
    const int* id = sidx + (size_t)b * NPTS;

    float d9 = 0.0f;
    int outi[9];
    for (int r = 2;; ++r) {
        float bd[10]; int bi[10];
#pragma unroll
        for (int j = 0; j < 10; ++j) { bd[j] = 3.4e38f; bi[j] = 0x7fffffff; }
        const int ylo = max(cy - r, 0), yhi = min(cy + r, GRIDW - 1);
        const int xlo = max(cx - r, 0), xhi = min(cx + r, GRIDW - 1);
        for (int ry = ylo; ry <= yhi; ++ry) {
            const int s0 = gs[ry * GRIDW + xlo];
            const int s1 = gs[ry * GRIDW + xhi + 1];
            for (int p0 = s0; p0 < s1; p0 += 64) {
                const int pp = p0 + lane;
                float d = 3.4e38f; int idx = 0x7fffffff;
                if (pp < s1) {
                    float2 cm = xy[pp];
                    idx = id[pp];
                    float sc  = __fadd_rn(__fmul_rn(cm.x, cm.x), __fmul_rn(cm.y, cm.y));
                    float dot = __fadd_rn(__fmul_rn(xn, cm.x), __fmul_rn(yn, cm.y));
                    float d2  = __fsub_rn(__fadd_rn(sn, sc), __fmul_rn(2.0f, dot));
                    d = sqrtf(fmaxf(d2, 0.0f));
                }
                if (d < bd[8]) {
#pragma unroll
                    for (int j = 8; j >= 1; --j) {
                        if (d < bd[j]) {
                            bool t2 = d < bd[j - 1];
                            bd[j] = t2 ? bd[j - 1] : d;
                            bi[j] = t2 ? bi[j - 1] : idx;
                        }
                    }
                    if (d < bd[0]) { bd[0] = d; bi[0] = idx; }
                }
            }
        }
        unsigned long long head =
            ((unsigned long long)__float_as_uint(bd[0]) << 32) | (unsigned)bi[0];
#pragma unroll
        for (int rr = 0; rr < 9; ++rr) {
            unsigned long long m = head;
#pragma unroll
            for (int s2 = 32; s2 > 0; s2 >>= 1) {
                unsigned long long o = __shfl_xor(m, s2, 64);
                m = o < m ? o : m;
            }
            outi[rr] = (int)(unsigned)(m & 0xffffffffULL);
            if (rr == 8) d9 = __uint_as_float((unsigned)(m >> 32));
            if (m == head) {
#pragma unroll
                for (int j = 0; j < 9; ++j) { bd[j] = bd[j + 1]; bi[j] = bi[j + 1]; }
                head = ((unsigned long long)__float_as_uint(bd[0]) << 32) | (unsigned)bi[0];
            }
        }
        if (d9 <= (float)r * CELLW - 0.01f || r >= 34) break;
    }
    if (lane == 0) {
        int* o = nn_out + (size_t)q * 16;
#pragma unroll
        for (int rr = 0; rr < 9; ++rr) o[rr] = outi[rr];
    }
}

// ---------------- GEMM: C[m][e] = sum_d A[m][d]*W[e][d] (bf16 MFMA) ----------
// 1-D grid with XCD-chunk swizzle: bid&7 = XCD, each XCD owns row-tiles
// [8k, 8k+8) x all col-tiles -> A working set (1MB) + B stay L2-resident.
__device__ __forceinline__ void gload16(const bf16* g, bf16* l) {
    __builtin_amdgcn_global_load_lds(
        (const __attribute__((address_space(1))) unsigned int*)g,
        (__attribute__((address_space(3))) unsigned int*)l,
        16, 0, 0);
}

template <bool EPI, int NCOLT>
__global__ __launch_bounds__(256) void gemm_bt(const bf16* __restrict__ A,
                                               const bf16* __restrict__ W,
                                               void* __restrict__ Cout,
                                               int Nn, int Kd,
                                               const float* __restrict__ bias,
                                               const float* __restrict__ resid) {
    __shared__ __attribute__((aligned(16))) bf16 As[2][128][32];
    __shared__ __attribute__((aligned(16))) bf16 Bs[2][128][32];

    const int tid = threadIdx.x;
    // XCD-chunk swizzle (bijective: grid = 8 * 8 * NCOLT blocks)
    const int bid = blockIdx.x;
    const int xcd = bid & 7;
    const int idx = bid >> 3;
    const int rowBase = (xcd * 8 + (idx & 7)) * 128;
    const int colBase = (idx >> 3) * 128;
    const int nk = Kd >> 5;

    const int lane = tid & 63, w = tid >> 6;
    const int wr = w >> 1, wc = w & 1;

    const int r0  = tid >> 2;        // 0..63
    const int kk0 = (tid & 3) * 8;   // 0,8,16,24

    f32x4 acc[4][4] = {};

    const bf16* gaBase = A + (size_t)(rowBase + r0) * Kd + kk0;
    const bf16* gbBase = W + (size_t)(colBase + r0) * Kd + kk0;

#define STAGE(bufi, kt)                                                     \
    do {                                                                    \
        const bf16* ga = gaBase + (size_t)(kt) * 32;                        \
        const bf16* gb = gbBase + (size_t)(kt) * 32;                        \
        gload16(ga,                   &As[bufi][r0][kk0]);                  \
        gload16(ga + (size_t)64 * Kd, &As[bufi][r0 + 64][kk0]);             \
        gload16(gb,                   &Bs[bufi][r0][kk0]);                  \
        gload16(gb + (size_t)64 * Kd, &Bs[bufi][r0 + 64][kk0]);             \
    } while (0)

    STAGE(0, 0);
    __syncthreads();

    int buf = 0;
    const int r16 = lane & 15;
    const int hk  = (lane >> 4) * 8;
    for (int kt = 0; kt < nk; ++kt) {
        if (kt + 1 < nk) STAGE(buf ^ 1, kt + 1);

        bf16x8 afr[4], bfr[4];
#pragma unroll
        for (int m2 = 0; m2 < 4; ++m2)
            afr[m2] = *(const bf16x8*)&As[buf][wr * 64 + m2 * 16 + r16][hk];
#pragma unroll
        for (int n2 = 0; n2 < 4; ++n2)
            bfr[n2] = *(const bf16x8*)&Bs[buf][wc * 64 + n2 * 16 + r16][hk];
#pragma unroll
        for (int m2 = 0; m2 < 4; ++m2)
#pragma unroll
            for (int n2 = 0; n2 < 4; ++n2)
                acc[m2][n2] = __builtin_amdgcn_mfma_f32_16x16x32_bf16(
                    afr[m2], bfr[n2], acc[m2][n2], 0, 0, 0);

        __syncthreads();
        buf ^= 1;
    }
#undef STAGE

    const int r4  = (lane >> 4) * 4;
    const int c16 = lane & 15;
#pragma unroll
    for (int m2 = 0; m2 < 4; ++m2) {
#pragma unroll
        for (int n2 = 0; n2 < 4; ++n2) {
            const int gc = colBase + wc * 64 + n2 * 16 + c16;
#pragma unroll
            for (int r = 0; r < 4; ++r) {
                const int gr = rowBase + wr * 64 + m2 * 16 + r4 + r;
                float v = acc[m2][n2][r];
                if (EPI) {
                    v = v + bias[gc];
                    v = resid[(size_t)gr * Nn + gc] + v;
                    ((float*)Cout)[(size_t)gr * Nn + gc] = v;
                } else {
                    ((bf16*)Cout)[(size_t)gr * Nn + gc] = __float2bfloat16(v);
                }
            }
        }
    }
}

// ---------------- attention + GELU: one wave per query, all 8 heads ----------
__global__ __launch_bounds__(256) void attn_kernel(const bf16* __restrict__ qkv,
                                                   const int* __restrict__ nn,
                                                   bf16* __restrict__ g) {
    const int wv = threadIdx.x >> 6, lane = threadIdx.x & 63;
    const int q = blockIdx.x * 4 + wv;   // 0..8191
    const int b = q >> 12;
    const int rowbase = b * NPTS;

    const int* nnq = nn + (size_t)q * 16;
    int idxs[KNN];
#pragma unroll
    for (int j = 0; j < KNN; ++j) idxs[j] = nnq[j];

    bf16x8 qv = *(const bf16x8*)(qkv + (size_t)q * 1536 + lane * 8);
    float qf[8];
#pragma unroll
    for (int e = 0; e < 8; ++e) qf[e] = (float)qv[e];

    float lg[KNN];
#pragma unroll
    for (int j = 0; j < KNN; ++j) {
        const bf16x8 kv = *(const bf16x8*)(
            qkv + (size_t)(rowbase + idxs[j]) * 1536 + DMODEL + lane * 8);
        float p = 0.0f;
#pragma unroll
        for (int e = 0; e < 8; ++e) p += qf[e] * (float)kv[e];
        p += __shfl_xor(p, 1, 64);
        p += __shfl_xor(p, 2, 64);
        p += __shfl_xor(p, 4, 64);
        lg[j] = p * 0.125f;  // / sqrt(64)
    }
    float mx = lg[0];
#pragma unroll
    for (int j = 1; j < KNN; ++j) mx = fmaxf(mx, lg[j]);
    float wgt[KNN], ssum = 0.0f;
#pragma unroll
    for (int j = 0; j < KNN; ++j) { wgt[j] = expf(lg[j] - mx); ssum += wgt[j]; }
    const float inv = 1.0f / ssum;

    float o[8] = {};
#pragma unroll
    for (int j = 0; j < KNN; ++j) {
        const bf16x8 vv = *(const bf16x8*)(
            qkv + (size_t)(rowbase + idxs[j]) * 1536 + 2 * DMODEL + lane * 8);
        const float wj = wgt[j] * inv;
#pragma unroll
        for (int e = 0; e < 8; ++e) o[e] += wj * (float)vv[e];
    }
    bf16x8 ov;
#pragma unroll
    for (int e = 0; e < 8; ++e) {
        float ge = 0.5f * o[e] * (1.0f + erff(o[e] * 0.70710678118654752f));
        ov[e] = (__bf16)__float2bfloat16(ge);
    }
    *(bf16x8*)(g + (size_t)q * DMODEL + lane * 8) = ov;
}

// ---------------- launch ----------------
extern "C" void kernel_launch(void* const* d_in, const int* in_sizes, int n_in,
                              void* d_out, int out_size, void* d_ws, size_t ws_size,
                              hipStream_t stream) {
    const float* x      = (const float*)d_in[0];
    const float* coords = (const float*)d_in[1];
    const float* w_qkv  = (const float*)d_in[2];
    const float* w_proj = (const float*)d_in[3];
    const float* b_proj = (const float*)d_in[4];
    float* out = (float*)d_out;

    char* wsb = (char*)d_ws;
    size_t off = 0;
    int*    nn     = (int*)(wsb + off);    off += NN_BYTES;
    bf16*   qkv    = (bf16*)(wsb + off);   off += QKV_BYTES;
    bf16*   g      = (bf16*)(wsb + off);   off += G_BYTES;
    bf16*   xb     = (bf16*)(wsb + off);   off += XB_BYTES;
    bf16*   wqb    = (bf16*)(wsb + off);   off += WQ_BYTES;
    bf16*   wpb    = (bf16*)(wsb + off);   off += WP_BYTES;
    int*    gstart = (int*)(wsb + off);    off += GSTART_BYTES;
    float2* sxy    = (float2*)(wsb + off); off += SXY_BYTES;
    int*    sidx   = (int*)(wsb + off);    off += SIDX_BYTES;

    // f32 -> bf16 converts: x (4194304), w_qkv (786432), w_proj (262144)
    const int n0 = 4194304 / 4, n1 = 786432 / 4, n2 = 262144 / 4;
    // total = 1310720 = 1280 * 1024; +2 grid_build blocks
    prep_kernel<<<1282, 1024, 0, stream>>>(
        (const float4*)x, (ushort4*)xb, n0,
        (const float4*)w_qkv, (ushort4*)wqb, n1,
        (const float4*)w_proj, (ushort4*)wpb, n2,
        coords, gstart, sxy, sidx);

    knn_grid<<<2048, 256, 0, stream>>>(coords, gstart, sxy, sidx, nn);
    gemm_bt<false, 12><<<768, 256, 0, stream>>>(xb, wqb, qkv, 1536, 512,
                                                nullptr, nullptr);
    attn_kernel<<<2048, 256, 0, stream>>>(qkv, nn, g);
    gemm_bt<true, 4><<<256, 256, 0, stream>>>(g, wpb, out, 512, 512,
                                              b_proj, x);
}

// Round 14
// 150.705 us; speedup vs baseline: 1.0744x; 1.0187x over previous
//
#include <hip/hip_runtime.h>
#include <hip/hip_bf16.h>

using bf16 = __hip_bfloat16;

typedef __attribute__((ext_vector_type(8))) __bf16 bf16x8;
typedef __attribute__((ext_vector_type(4))) float f32x4;

#define NPTS 4096
#define DMODEL 512
#define HDIM 64
#define KNN 9
#define MROWS 8192  // B*N

#define GRIDW 32
#define CELLW 3.125f   // 100/32, exact in f32
#define NCELL (GRIDW * GRIDW)

// ---------------- workspace layout (all sizes bytes) ----------------
#define NN_BYTES    (MROWS * 16 * 4)             // 512 KB
#define QKV_BYTES   ((size_t)MROWS * 1536 * 2)   // 25.2 MB
#define G_BYTES     ((size_t)MROWS * 512 * 2)    // 8.4 MB
#define XB_BYTES    ((size_t)MROWS * 512 * 2)    // 8.4 MB
#define WQ_BYTES    ((size_t)1536 * 512 * 2)     // 1.5 MB
#define WP_BYTES    ((size_t)512 * 512 * 2)      // 0.5 MB
#define GSTART_BYTES (2 * 1025 * 4)
#define SXY_BYTES    ((size_t)2 * NPTS * 8)
#define SIDX_BYTES   ((size_t)2 * NPTS * 4)

// ---------------- prep: cvt (blocks 0..1279) + grid_build (blocks 1280..1281) --
__global__ __launch_bounds__(1024) void prep_kernel(
    const float4* __restrict__ s0, ushort4* __restrict__ d0, int n0,
    const float4* __restrict__ s1, ushort4* __restrict__ d1, int n1,
    const float4* __restrict__ s2, ushort4* __restrict__ d2, int n2,
    const float* __restrict__ coords,
    int* __restrict__ gstart,   // [2][1025]
    float2* __restrict__ sxy,   // [2][4096]
    int* __restrict__ sidx) {   // [2][4096]
    __shared__ int cnt[NCELL];
    __shared__ int off2[NCELL];
    __shared__ int sstart[NCELL];
    __shared__ int wsum[16];

    if (blockIdx.x < 1280) {
        int g = blockIdx.x * 1024 + threadIdx.x;
        const float4* s; ushort4* d; int i;
        if (g < n0) { s = s0; d = d0; i = g; }
        else if (g < n0 + n1) { s = s1; d = d1; i = g - n0; }
        else { s = s2; d = d2; i = g - n0 - n1; }
        float4 v = s[i];
        bf16 b0 = __float2bfloat16(v.x), b1 = __float2bfloat16(v.y);
        bf16 b2 = __float2bfloat16(v.z), b3 = __float2bfloat16(v.w);
        ushort4 o;
        o.x = *reinterpret_cast<unsigned short*>(&b0);
        o.y = *reinterpret_cast<unsigned short*>(&b1);
        o.z = *reinterpret_cast<unsigned short*>(&b2);
        o.w = *reinterpret_cast<unsigned short*>(&b3);
        d[i] = o;
        return;
    }

    const int b = blockIdx.x - 1280, tid = threadIdx.x;
    cnt[tid] = 0; off2[tid] = 0;
    __syncthreads();
    const float2* c2 = (const float2*)(coords + (size_t)b * NPTS * 2);
    float px[4], py[4]; int pc[4];
#pragma unroll
    for (int i = 0; i < 4; ++i) {
        int p = tid + i * 1024;
        float2 v = c2[p];
        px[i] = v.x; py[i] = v.y;
        int cx = min(GRIDW - 1, (int)(v.x / CELLW));
        int cy = min(GRIDW - 1, (int)(v.y / CELLW));
        pc[i] = cy * GRIDW + cx;
        atomicAdd(&cnt[pc[i]], 1);
    }
    __syncthreads();
    const int v = cnt[tid];
    const int lane = tid & 63, wv = tid >> 6;
    int inc = v;
#pragma unroll
    for (int o = 1; o < 64; o <<= 1) {
        int t = __shfl_up(inc, o, 64);
        if (lane >= o) inc += t;
    }
    if (lane == 63) wsum[wv] = inc;
    __syncthreads();
    if (tid < 16) {
        int w = wsum[tid];
#pragma unroll
        for (int o = 1; o < 16; o <<= 1) {
            int t = __shfl_up(w, o, 16);
            if (tid >= o) w += t;
        }
        wsum[tid] = w;
    }
    __syncthreads();
    const int excl = inc - v + (wv ? wsum[wv - 1] : 0);
    sstart[tid] = excl;
    gstart[b * 1025 + tid] = excl;
    if (tid == 1023) gstart[b * 1025 + 1024] = excl + v;
    __syncthreads();
#pragma unroll
    for (int i = 0; i < 4; ++i) {
        int o = atomicAdd(&off2[pc[i]], 1);
        int pos = sstart[pc[i]] + o;
        sxy[(size_t)b * NPTS + pos]  = make_float2(px[i], py[i]);
        sidx[(size_t)b * NPTS + pos] = tid + i * 1024;
    }
}

// ---------------- kNN via grid: one wave per query (no LDS -> high occupancy) --
__global__ __launch_bounds__(256) void knn_grid(const float* __restrict__ coords,
                                                const int* __restrict__ gstart,
                                                const float2* __restrict__ sxy,
                                                const int* __restrict__ sidx,
                                                int* __restrict__ nn_out) {
    const int wv = threadIdx.x >> 6, lane = threadIdx.x & 63;
    const int q = blockIdx.x * 4 + wv;  // 0..8191
    const int b = q >> 12, n = q & 4095;
    const float2* cb = (const float2*)(coords + (size_t)b * NPTS * 2);
    const float2 pq = cb[n];
    const float xn = pq.x, yn = pq.y;
    const float sn = __fadd_rn(__fmul_rn(xn, xn), __fmul_rn(yn, yn));
    const int cx = min(GRIDW - 1, (int)(xn / CELLW));
    const int cy = min(GRIDW - 1, (int)(yn / CELLW));
    const int* gs = gstart + b * 1025;
    const float2* xy = sxy + (size_t)b * NPTS;
    const int* id = sidx + (size_t)b * NPTS;

    float d9 = 0.0f;
    int outi[9];
    for (int r = 2;; ++r) {
        float bd[10]; int bi[10];
#pragma unroll
        for (int j = 0; j < 10; ++j) { bd[j] = 3.4e38f; bi[j] = 0x7fffffff; }
        const int ylo = max(cy - r, 0), yhi = min(cy + r, GRIDW - 1);
        const int xlo = max(cx - r, 0), xhi = min(cx + r, GRIDW - 1);
        for (int ry = ylo; ry <= yhi; ++ry) {
            const int s0 = gs[ry * GRIDW + xlo];
            const int s1 = gs[ry * GRIDW + xhi + 1];
            for (int p0 = s0; p0 < s1; p0 += 64) {
                const int pp = p0 + lane;
                float d = 3.4e38f; int idx = 0x7fffffff;
                if (pp < s1) {
                    float2 cm = xy[pp];
                    idx = id[pp];
                    float sc  = __fadd_rn(__fmul_rn(cm.x, cm.x), __fmul_rn(cm.y, cm.y));
                    float dot = __fadd_rn(__fmul_rn(xn, cm.x), __fmul_rn(yn, cm.y));
                    float d2  = __fsub_rn(__fadd_rn(sn, sc), __fmul_rn(2.0f, dot));
                    d = sqrtf(fmaxf(d2, 0.0f));
                }
                if (d < bd[8]) {
#pragma unroll
                    for (int j = 8; j >= 1; --j) {
                        if (d < bd[j]) {
                            bool t2 = d < bd[j - 1];
                            bd[j] = t2 ? bd[j - 1] : d;
                            bi[j] = t2 ? bi[j - 1] : idx;
                        }
                    }
                    if (d < bd[0]) { bd[0] = d; bi[0] = idx; }
                }
            }
        }
        unsigned long long head =
            ((unsigned long long)__float_as_uint(bd[0]) << 32) | (unsigned)bi[0];
#pragma unroll
        for (int rr = 0; rr < 9; ++rr) {
            unsigned long long m = head;
#pragma unroll
            for (int s2 = 32; s2 > 0; s2 >>= 1) {
                unsigned long long o = __shfl_xor(m, s2, 64);
                m = o < m ? o : m;
            }
            outi[rr] = (int)(unsigned)(m & 0xffffffffULL);
            if (rr == 8) d9 = __uint_as_float((unsigned)(m >> 32));
            if (m == head) {
#pragma unroll
                for (int j = 0; j < 9; ++j) { bd[j] = bd[j + 1]; bi[j] = bi[j + 1]; }
                head = ((unsigned long long)__float_as_uint(bd[0]) << 32) | (unsigned)bi[0];
            }
        }
        if (d9 <= (float)r * CELLW - 0.01f || r >= 34) break;
    }
    if (lane == 0) {
        int* o = nn_out + (size_t)q * 16;
#pragma unroll
        for (int rr = 0; rr < 9; ++rr) o[rr] = outi[rr];
    }
}

// ---------------- GEMM: C[m][e] = sum_d A[m][d]*W[e][d] (bf16 MFMA) ----------
__device__ __forceinline__ void gload16(const bf16* g, bf16* l) {
    __builtin_amdgcn_global_load_lds(
        (const __attribute__((address_space(1))) unsigned int*)g,
        (__attribute__((address_space(3))) unsigned int*)l,
        16, 0, 0);
}

template <bool EPI, int NCOLT>
__global__ __launch_bounds__(256) void gemm_bt(const bf16* __restrict__ A,
                                               const bf16* __restrict__ W,
                                               void* __restrict__ Cout,
                                               int Nn, int Kd,
                                               const float* __restrict__ bias,
                                               const float* __restrict__ resid) {
    __shared__ __attribute__((aligned(16))) bf16 As[2][128][32];
    __shared__ __attribute__((aligned(16))) bf16 Bs[2][128][32];

    const int tid = threadIdx.x;
    const int bid = blockIdx.x;
    const int xcd = bid & 7;
    const int idx = bid >> 3;
    const int rowBase = (xcd * 8 + (idx & 7)) * 128;
    const int colBase = (idx >> 3) * 128;
    const int nk = Kd >> 5;

    const int lane = tid & 63, w = tid >> 6;
    const int wr = w >> 1, wc = w & 1;

    const int r0  = tid >> 2;        // 0..63
    const int kk0 = (tid & 3) * 8;   // 0,8,16,24

    f32x4 acc[4][4] = {};

    const bf16* gaBase = A + (size_t)(rowBase + r0) * Kd + kk0;
    const bf16* gbBase = W + (size_t)(colBase + r0) * Kd + kk0;

#define STAGE(bufi, kt)                                                     \
    do {                                                                    \
        const bf16* ga = gaBase + (size_t)(kt) * 32;                        \
        const bf16* gb = gbBase + (size_t)(kt) * 32;                        \
        gload16(ga,                   &As[bufi][r0][kk0]);                  \
        gload16(ga + (size_t)64 * Kd, &As[bufi][r0 + 64][kk0]);             \
        gload16(gb,                   &Bs[bufi][r0][kk0]);                  \
        gload16(gb + (size_t)64 * Kd, &Bs[bufi][r0 + 64][kk0]);             \
    } while (0)

    STAGE(0, 0);
    __syncthreads();

    int buf = 0;
    const int r16 = lane & 15;
    const int hk  = (lane >> 4) * 8;
    for (int kt = 0; kt < nk; ++kt) {
        if (kt + 1 < nk) STAGE(buf ^ 1, kt + 1);

        bf16x8 afr[4], bfr[4];
#pragma unroll
        for (int m2 = 0; m2 < 4; ++m2)
            afr[m2] = *(const bf16x8*)&As[buf][wr * 64 + m2 * 16 + r16][hk];
#pragma unroll
        for (int n2 = 0; n2 < 4; ++n2)
            bfr[n2] = *(const bf16x8*)&Bs[buf][wc * 64 + n2 * 16 + r16][hk];
#pragma unroll
        for (int m2 = 0; m2 < 4; ++m2)
#pragma unroll
            for (int n2 = 0; n2 < 4; ++n2)
                acc[m2][n2] = __builtin_amdgcn_mfma_f32_16x16x32_bf16(
                    afr[m2], bfr[n2], acc[m2][n2], 0, 0, 0);

        __syncthreads();
        buf ^= 1;
    }
#undef STAGE

    const int r4  = (lane >> 4) * 4;
    const int c16 = lane & 15;
#pragma unroll
    for (int m2 = 0; m2 < 4; ++m2) {
#pragma unroll
        for (int n2 = 0; n2 < 4; ++n2) {
            const int gc = colBase + wc * 64 + n2 * 16 + c16;
#pragma unroll
            for (int r = 0; r < 4; ++r) {
                const int gr = rowBase + wr * 64 + m2 * 16 + r4 + r;
                float v = acc[m2][n2][r];
                if (EPI) {
                    v = v + bias[gc];
                    v = resid[(size_t)gr * Nn + gc] + v;
                    ((float*)Cout)[(size_t)gr * Nn + gc] = v;
                } else {
                    ((bf16*)Cout)[(size_t)gr * Nn + gc] = __float2bfloat16(v);
                }
            }
        }
    }
}

// ---------------- attention + GELU: one wave per query, grid-sorted order ------
// Wave handles q = b*4096 + sidx[b][pos]: consecutive waves process spatially
// adjacent points whose 9-neighbor sets overlap -> K/V gathers hit L2 instead
// of crawling cross-XCD. Per-query arithmetic identical to the linear-order
// version (pure work->wave permutation).
__global__ __launch_bounds__(256) void attn_kernel(const bf16* __restrict__ qkv,
                                                   const int* __restrict__ nn,
                                                   const int* __restrict__ sidx,
                                                   bf16* __restrict__ g) {
    const int wv = threadIdx.x >> 6, lane = threadIdx.x & 63;
    const int pos = blockIdx.x * 4 + wv;   // 0..8191 (sorted position)
    const int b = pos >> 12;
    const int q = b * NPTS + sidx[(size_t)b * NPTS + (pos & 4095)];
    const int rowbase = b * NPTS;

    const int* nnq = nn + (size_t)q * 16;
    int idxs[KNN];
#pragma unroll
    for (int j = 0; j < KNN; ++j) idxs[j] = nnq[j];

    bf16x8 qv = *(const bf16x8*)(qkv + (size_t)q * 1536 + lane * 8);
    float qf[8];
#pragma unroll
    for (int e = 0; e < 8; ++e) qf[e] = (float)qv[e];

    float lg[KNN];
#pragma unroll
    for (int j = 0; j < KNN; ++j) {
        const bf16x8 kv = *(const bf16x8*)(
            qkv + (size_t)(rowbase + idxs[j]) * 1536 + DMODEL + lane * 8);
        float p = 0.0f;
#pragma unroll
        for (int e = 0; e < 8; ++e) p += qf[e] * (float)kv[e];
        p += __shfl_xor(p, 1, 64);
        p += __shfl_xor(p, 2, 64);
        p += __shfl_xor(p, 4, 64);
        lg[j] = p * 0.125f;  // / sqrt(64)
    }
    float mx = lg[0];
#pragma unroll
    for (int j = 1; j < KNN; ++j) mx = fmaxf(mx, lg[j]);
    float wgt[KNN], ssum = 0.0f;
#pragma unroll
    for (int j = 0; j < KNN; ++j) { wgt[j] = expf(lg[j] - mx); ssum += wgt[j]; }
    const float inv = 1.0f / ssum;

    float o[8] = {};
#pragma unroll
    for (int j = 0; j < KNN; ++j) {
        const bf16x8 vv = *(const bf16x8*)(
            qkv + (size_t)(rowbase + idxs[j]) * 1536 + 2 * DMODEL + lane * 8);
        const float wj = wgt[j] * inv;
#pragma unroll
        for (int e = 0; e < 8; ++e) o[e] += wj * (float)vv[e];
    }
    bf16x8 ov;
#pragma unroll
    for (int e = 0; e < 8; ++e) {
        float ge = 0.5f * o[e] * (1.0f + erff(o[e] * 0.70710678118654752f));
        ov[e] = (__bf16)__float2bfloat16(ge);
    }
    *(bf16x8*)(g + (size_t)q * DMODEL + lane * 8) = ov;
}

// ---------------- launch ----------------
extern "C" void kernel_launch(void* const* d_in, const int* in_sizes, int n_in,
                              void* d_out, int out_size, void* d_ws, size_t ws_size,
                              hipStream_t stream) {
    const float* x      = (const float*)d_in[0];
    const float* coords = (const float*)d_in[1];
    const float* w_qkv  = (const float*)d_in[2];
    const float* w_proj = (const float*)d_in[3];
    const float* b_proj = (const float*)d_in[4];
    float* out = (float*)d_out;

    char* wsb = (char*)d_ws;
    size_t off = 0;
    int*    nn     = (int*)(wsb + off);    off += NN_BYTES;
    bf16*   qkv    = (bf16*)(wsb + off);   off += QKV_BYTES;
    bf16*   g      = (bf16*)(wsb + off);   off += G_BYTES;
    bf16*   xb     = (bf16*)(wsb + off);   off += XB_BYTES;
    bf16*   wqb    = (bf16*)(wsb + off);   off += WQ_BYTES;
    bf16*   wpb    = (bf16*)(wsb + off);   off += WP_BYTES;
    int*    gstart = (int*)(wsb + off);    off += GSTART_BYTES;
    float2* sxy    = (float2*)(wsb + off); off += SXY_BYTES;
    int*    sidx   = (int*)(wsb + off);    off += SIDX_BYTES;

    // f32 -> bf16 converts: x (4194304), w_qkv (786432), w_proj (262144)
    const int n0 = 4194304 / 4, n1 = 786432 / 4, n2 = 262144 / 4;
    // total = 1310720 = 1280 * 1024; +2 grid_build blocks
    prep_kernel<<<1282, 1024, 0, stream>>>(
        (const float4*)x, (ushort4*)xb, n0,
        (const float4*)w_qkv, (ushort4*)wqb, n1,
        (const float4*)w_proj, (ushort4*)wpb, n2,
        coords, gstart, sxy, sidx);

    knn_grid<<<2048, 256, 0, stream>>>(coords, gstart, sxy, sidx, nn);
    gemm_bt<false, 12><<<768, 256, 0, stream>>>(xb, wqb, qkv, 1536, 512,
                                                nullptr, nullptr);
    attn_kernel<<<2048, 256, 0, stream>>>(qkv, nn, sidx, g);
    gemm_bt<true, 4><<<256, 256, 0, stream>>>(g, wpb, out, 512, 512,
                                              b_proj, x);
}

// Round 15
// 149.179 us; speedup vs baseline: 1.0854x; 1.0102x over previous
//
#include <hip/hip_runtime.h>
#include <hip/hip_bf16.h>

using bf16 = __hip_bfloat16;

typedef __attribute__((ext_vector_type(8))) __bf16 bf16x8;
typedef __attribute__((ext_vector_type(4))) float f32x4;

#define NPTS 4096
#define DMODEL 512
#define HDIM 64
#define KNN 9
#define MROWS 8192  // B*N

#define GRIDW 32
#define CELLW 3.125f   // 100/32, exact in f32
#define NCELL (GRIDW * GRIDW)

// ---------------- workspace layout (all sizes bytes) ----------------
#define NN_BYTES    (MROWS * 16 * 4)             // 512 KB
#define QKV_BYTES   ((size_t)MROWS * 1536 * 2)   // 25.2 MB
#define G_BYTES     ((size_t)MROWS * 512 * 2)    // 8.4 MB
#define XB_BYTES    ((size_t)MROWS * 512 * 2)    // 8.4 MB
#define WQ_BYTES    ((size_t)1536 * 512 * 2)     // 1.5 MB
#define WP_BYTES    ((size_t)512 * 512 * 2)      // 0.5 MB
#define GSTART_BYTES (2 * 1025 * 4)
#define SXY_BYTES    ((size_t)2 * NPTS * 8)
#define SIDX_BYTES   ((size_t)2 * NPTS * 4)

// ---------------- prep: cvt (blocks 0..1279) + grid_build (blocks 1280..1281) --
__global__ __launch_bounds__(1024) void prep_kernel(
    const float4* __restrict__ s0, ushort4* __restrict__ d0, int n0,
    const float4* __restrict__ s1, ushort4* __restrict__ d1, int n1,
    const float4* __restrict__ s2, ushort4* __restrict__ d2, int n2,
    const float* __restrict__ coords,
    int* __restrict__ gstart,   // [2][1025]
    float2* __restrict__ sxy,   // [2][4096]
    int* __restrict__ sidx) {   // [2][4096]
    __shared__ int cnt[NCELL];
    __shared__ int off2[NCELL];
    __shared__ int sstart[NCELL];
    __shared__ int wsum[16];

    if (blockIdx.x < 1280) {
        int g = blockIdx.x * 1024 + threadIdx.x;
        const float4* s; ushort4* d; int i;
        if (g < n0) { s = s0; d = d0; i = g; }
        else if (g < n0 + n1) { s = s1; d = d1; i = g - n0; }
        else { s = s2; d = d2; i = g - n0 - n1; }
        float4 v = s[i];
        bf16 b0 = __float2bfloat16(v.x), b1 = __float2bfloat16(v.y);
        bf16 b2 = __float2bfloat16(v.z), b3 = __float2bfloat16(v.w);
        ushort4 o;
        o.x = *reinterpret_cast<unsigned short*>(&b0);
        o.y = *reinterpret_cast<unsigned short*>(&b1);
        o.z = *reinterpret_cast<unsigned short*>(&b2);
        o.w = *reinterpret_cast<unsigned short*>(&b3);
        d[i] = o;
        return;
    }

    const int b = blockIdx.x - 1280, tid = threadIdx.x;
    cnt[tid] = 0; off2[tid] = 0;
    __syncthreads();
    const float2* c2 = (const float2*)(coords + (size_t)b * NPTS * 2);
    float px[4], py[4]; int pc[4];
#pragma unroll
    for (int i = 0; i < 4; ++i) {
        int p = tid + i * 1024;
        float2 v = c2[p];
        px[i] = v.x; py[i] = v.y;
        int cx = min(GRIDW - 1, (int)(v.x / CELLW));
        int cy = min(GRIDW - 1, (int)(v.y / CELLW));
        pc[i] = cy * GRIDW + cx;
        atomicAdd(&cnt[pc[i]], 1);
    }
    __syncthreads();
    const int v = cnt[tid];
    const int lane = tid & 63, wv = tid >> 6;
    int inc = v;
#pragma unroll
    for (int o = 1; o < 64; o <<= 1) {
        int t = __shfl_up(inc, o, 64);
        if (lane >= o) inc += t;
    }
    if (lane == 63) wsum[wv] = inc;
    __syncthreads();
    if (tid < 16) {
        int w = wsum[tid];
#pragma unroll
        for (int o = 1; o < 16; o <<= 1) {
            int t = __shfl_up(w, o, 16);
            if (tid >= o) w += t;
        }
        wsum[tid] = w;
    }
    __syncthreads();
    const int excl = inc - v + (wv ? wsum[wv - 1] : 0);
    sstart[tid] = excl;
    gstart[b * 1025 + tid] = excl;
    if (tid == 1023) gstart[b * 1025 + 1024] = excl + v;
    __syncthreads();
#pragma unroll
    for (int i = 0; i < 4; ++i) {
        int o = atomicAdd(&off2[pc[i]], 1);
        int pos = sstart[pc[i]] + o;
        sxy[(size_t)b * NPTS + pos]  = make_float2(px[i], py[i]);
        sidx[(size_t)b * NPTS + pos] = tid + i * 1024;
    }
}

// ---------------- kNN in position space: one wave per sorted position ---------
// Query coords read from sxy (bit-identical values). Outputs neighbor POSITIONS
// (batch-relative, 0..4095). Key packs (dist, pos): ascending-distance order
// preserved; tie-break differs from reference only on exact f32 distance ties
// (measure-zero). Self-distance computes exactly 0 -> self stays neighbor #0.
__global__ __launch_bounds__(256) void knn_grid(const int* __restrict__ gstart,
                                                const float2* __restrict__ sxy,
                                                int* __restrict__ nn_out) {
    const int wv = threadIdx.x >> 6, lane = threadIdx.x & 63;
    const int pos = blockIdx.x * 4 + wv;  // 0..8191
    const int b = pos >> 12, p = pos & 4095;
    const float2* xy = sxy + (size_t)b * NPTS;
    const float2 pq = xy[p];
    const float xn = pq.x, yn = pq.y;
    const float sn = __fadd_rn(__fmul_rn(xn, xn), __fmul_rn(yn, yn));
    const int cx = min(GRIDW - 1, (int)(xn / CELLW));
    const int cy = min(GRIDW - 1, (int)(yn / CELLW));
    const int* gs = gstart + b * 1025;

    float d9 = 0.0f;
    int outi[9];
    for (int r = 2;; ++r) {
        float bd[10]; int bi[10];
#pragma unroll
        for (int j = 0; j < 10; ++j) { bd[j] = 3.4e38f; bi[j] = 0x7fffffff; }
        const int ylo = max(cy - r, 0), yhi = min(cy + r, GRIDW - 1);
        const int xlo = max(cx - r, 0), xhi = min(cx + r, GRIDW - 1);
        for (int ry = ylo; ry <= yhi; ++ry) {
            const int s0 = gs[ry * GRIDW + xlo];
            const int s1 = gs[ry * GRIDW + xhi + 1];
            for (int p0 = s0; p0 < s1; p0 += 64) {
                const int pp = p0 + lane;
                float d = 3.4e38f; int idx = 0x7fffffff;
                if (pp < s1) {
                    float2 cm = xy[pp];
                    idx = pp;   // POSITION, not original index
                    float sc  = __fadd_rn(__fmul_rn(cm.x, cm.x), __fmul_rn(cm.y, cm.y));
                    float dot = __fadd_rn(__fmul_rn(xn, cm.x), __fmul_rn(yn, cm.y));
                    float d2  = __fsub_rn(__fadd_rn(sn, sc), __fmul_rn(2.0f, dot));
                    d = sqrtf(fmaxf(d2, 0.0f));
                }
                if (d < bd[8]) {
#pragma unroll
                    for (int j = 8; j >= 1; --j) {
                        if (d < bd[j]) {
                            bool t2 = d < bd[j - 1];
                            bd[j] = t2 ? bd[j - 1] : d;
                            bi[j] = t2 ? bi[j - 1] : idx;
                        }
                    }
                    if (d < bd[0]) { bd[0] = d; bi[0] = idx; }
                }
            }
        }
        unsigned long long head =
            ((unsigned long long)__float_as_uint(bd[0]) << 32) | (unsigned)bi[0];
#pragma unroll
        for (int rr = 0; rr < 9; ++rr) {
            unsigned long long m = head;
#pragma unroll
            for (int s2 = 32; s2 > 0; s2 >>= 1) {
                unsigned long long o = __shfl_xor(m, s2, 64);
                m = o < m ? o : m;
            }
            outi[rr] = (int)(unsigned)(m & 0xffffffffULL);
            if (rr == 8) d9 = __uint_as_float((unsigned)(m >> 32));
            if (m == head) {
#pragma unroll
                for (int j = 0; j < 9; ++j) { bd[j] = bd[j + 1]; bi[j] = bi[j + 1]; }
                head = ((unsigned long long)__float_as_uint(bd[0]) << 32) | (unsigned)bi[0];
            }
        }
        if (d9 <= (float)r * CELLW - 0.01f || r >= 34) break;
    }
    if (lane == 0) {
        int* o = nn_out + (size_t)pos * 16;
#pragma unroll
        for (int rr = 0; rr < 9; ++rr) o[rr] = outi[rr];
    }
}

// ---------------- GEMM: C[m][e] = sum_d A[pr(m)][d]*W[e][d] (bf16 MFMA) -------
// PERM: A-rows gathered via perm (batch-relative sidx) so C comes out in
// grid-sorted order. global_load_lds source addresses are per-lane -> legal.
__device__ __forceinline__ void gload16(const bf16* g, bf16* l) {
    __builtin_amdgcn_global_load_lds(
        (const __attribute__((address_space(1))) unsigned int*)g,
        (__attribute__((address_space(3))) unsigned int*)l,
        16, 0, 0);
}

template <bool EPI, bool PERM>
__global__ __launch_bounds__(256) void gemm_bt(const bf16* __restrict__ A,
                                               const bf16* __restrict__ W,
                                               void* __restrict__ Cout,
                                               int Nn, int Kd,
                                               const float* __restrict__ bias,
                                               const float* __restrict__ resid,
                                               const int* __restrict__ perm) {
    __shared__ __attribute__((aligned(16))) bf16 As[2][128][32];
    __shared__ __attribute__((aligned(16))) bf16 Bs[2][128][32];

    const int tid = threadIdx.x;
    const int bid = blockIdx.x;
    const int xcd = bid & 7;
    const int idx = bid >> 3;
    const int rowBase = (xcd * 8 + (idx & 7)) * 128;
    const int colBase = (idx >> 3) * 128;
    const int nk = Kd >> 5;

    const int lane = tid & 63, w = tid >> 6;
    const int wr = w >> 1, wc = w & 1;

    const int r0  = tid >> 2;        // 0..63
    const int kk0 = (tid & 3) * 8;   // 0,8,16,24

    f32x4 acc[4][4] = {};

    const int row0 = rowBase + r0, row1 = rowBase + r0 + 64;
    const int pr0 = PERM ? ((row0 & ~4095) + perm[row0]) : row0;
    const int pr1 = PERM ? ((row1 & ~4095) + perm[row1]) : row1;

    const bf16* gaBase0 = A + (size_t)pr0 * Kd + kk0;
    const bf16* gaBase1 = A + (size_t)pr1 * Kd + kk0;
    const bf16* gbBase  = W + (size_t)(colBase + r0) * Kd + kk0;

#define STAGE(bufi, kt)                                                     \
    do {                                                                    \
        gload16(gaBase0 + (size_t)(kt) * 32, &As[bufi][r0][kk0]);           \
        gload16(gaBase1 + (size_t)(kt) * 32, &As[bufi][r0 + 64][kk0]);      \
        const bf16* gb = gbBase + (size_t)(kt) * 32;                        \
        gload16(gb,                   &Bs[bufi][r0][kk0]);                  \
        gload16(gb + (size_t)64 * Kd, &Bs[bufi][r0 + 64][kk0]);             \
    } while (0)

    STAGE(0, 0);
    __syncthreads();

    int buf = 0;
    const int r16 = lane & 15;
    const int hk  = (lane >> 4) * 8;
    for (int kt = 0; kt < nk; ++kt) {
        if (kt + 1 < nk) STAGE(buf ^ 1, kt + 1);

        bf16x8 afr[4], bfr[4];
#pragma unroll
        for (int m2 = 0; m2 < 4; ++m2)
            afr[m2] = *(const bf16x8*)&As[buf][wr * 64 + m2 * 16 + r16][hk];
#pragma unroll
        for (int n2 = 0; n2 < 4; ++n2)
            bfr[n2] = *(const bf16x8*)&Bs[buf][wc * 64 + n2 * 16 + r16][hk];
#pragma unroll
        for (int m2 = 0; m2 < 4; ++m2)
#pragma unroll
            for (int n2 = 0; n2 < 4; ++n2)
                acc[m2][n2] = __builtin_amdgcn_mfma_f32_16x16x32_bf16(
                    afr[m2], bfr[n2], acc[m2][n2], 0, 0, 0);

        __syncthreads();
        buf ^= 1;
    }
#undef STAGE

    const int r4  = (lane >> 4) * 4;
    const int c16 = lane & 15;
#pragma unroll
    for (int m2 = 0; m2 < 4; ++m2) {
#pragma unroll
        for (int n2 = 0; n2 < 4; ++n2) {
            const int gc = colBase + wc * 64 + n2 * 16 + c16;
#pragma unroll
            for (int r = 0; r < 4; ++r) {
                const int gr = rowBase + wr * 64 + m2 * 16 + r4 + r;
                float v = acc[m2][n2][r];
                if (EPI) {
                    v = v + bias[gc];
                    v = resid[(size_t)gr * Nn + gc] + v;
                    ((float*)Cout)[(size_t)gr * Nn + gc] = v;
                } else {
                    ((bf16*)Cout)[(size_t)gr * Nn + gc] = __float2bfloat16(v);
                }
            }
        }
    }
}

// ---------------- attention + GELU: position space, sorted qkv ----------------
// qkv_sorted row i = QKV of original point sidx[i]; neighbors are positions
// within a few-hundred-KB window -> gathers hit L2. Output scattered to
// g[original] so proj GEMM stays in original order.
__global__ __launch_bounds__(256) void attn_kernel(const bf16* __restrict__ qkv,
                                                   const int* __restrict__ nn,
                                                   const int* __restrict__ sidx,
                                                   bf16* __restrict__ g) {
    const int wv = threadIdx.x >> 6, lane = threadIdx.x & 63;
    const int pos = blockIdx.x * 4 + wv;   // 0..8191 (global sorted row)
    const int b = pos >> 12;
    const int rowbase = b * NPTS;

    const int* nnq = nn + (size_t)pos * 16;
    int idxs[KNN];
#pragma unroll
    for (int j = 0; j < KNN; ++j) idxs[j] = nnq[j];   // batch-relative positions

    bf16x8 qv = *(const bf16x8*)(qkv + (size_t)pos * 1536 + lane * 8);
    float qf[8];
#pragma unroll
    for (int e = 0; e < 8; ++e) qf[e] = (float)qv[e];

    float lg[KNN];
#pragma unroll
    for (int j = 0; j < KNN; ++j) {
        const bf16x8 kv = *(const bf16x8*)(
            qkv + (size_t)(rowbase + idxs[j]) * 1536 + DMODEL + lane * 8);
        float p = 0.0f;
#pragma unroll
        for (int e = 0; e < 8; ++e) p += qf[e] * (float)kv[e];
        p += __shfl_xor(p, 1, 64);
        p += __shfl_xor(p, 2, 64);
        p += __shfl_xor(p, 4, 64);
        lg[j] = p * 0.125f;  // / sqrt(64)
    }
    float mx = lg[0];
#pragma unroll
    for (int j = 1; j < KNN; ++j) mx = fmaxf(mx, lg[j]);
    float wgt[KNN], ssum = 0.0f;
#pragma unroll
    for (int j = 0; j < KNN; ++j) { wgt[j] = expf(lg[j] - mx); ssum += wgt[j]; }
    const float inv = 1.0f / ssum;

    float o[8] = {};
#pragma unroll
    for (int j = 0; j < KNN; ++j) {
        const bf16x8 vv = *(const bf16x8*)(
            qkv + (size_t)(rowbase + idxs[j]) * 1536 + 2 * DMODEL + lane * 8);
        const float wj = wgt[j] * inv;
#pragma unroll
        for (int e = 0; e < 8; ++e) o[e] += wj * (float)vv[e];
    }
    bf16x8 ov;
#pragma unroll
    for (int e = 0; e < 8; ++e) {
        float ge = 0.5f * o[e] * (1.0f + erff(o[e] * 0.70710678118654752f));
        ov[e] = (__bf16)__float2bfloat16(ge);
    }
    const int orig = sidx[pos];  // batch-relative original index
    *(bf16x8*)(g + (size_t)(rowbase + orig) * DMODEL + lane * 8) = ov;
}

// ---------------- launch ----------------
extern "C" void kernel_launch(void* const* d_in, const int* in_sizes, int n_in,
                              void* d_out, int out_size, void* d_ws, size_t ws_size,
                              hipStream_t stream) {
    const float* x      = (const float*)d_in[0];
    const float* coords = (const float*)d_in[1];
    const float* w_qkv  = (const float*)d_in[2];
    const float* w_proj = (const float*)d_in[3];
    const float* b_proj = (const float*)d_in[4];
    float* out = (float*)d_out;

    char* wsb = (char*)d_ws;
    size_t off = 0;
    int*    nn     = (int*)(wsb + off);    off += NN_BYTES;
    bf16*   qkv    = (bf16*)(wsb + off);   off += QKV_BYTES;
    bf16*   g      = (bf16*)(wsb + off);   off += G_BYTES;
    bf16*   xb     = (bf16*)(wsb + off);   off += XB_BYTES;
    bf16*   wqb    = (bf16*)(wsb + off);   off += WQ_BYTES;
    bf16*   wpb    = (bf16*)(wsb + off);   off += WP_BYTES;
    int*    gstart = (int*)(wsb + off);    off += GSTART_BYTES;
    float2* sxy    = (float2*)(wsb + off); off += SXY_BYTES;
    int*    sidx   = (int*)(wsb + off);    off += SIDX_BYTES;

    // f32 -> bf16 converts: x (4194304), w_qkv (786432), w_proj (262144)
    const int n0 = 4194304 / 4, n1 = 786432 / 4, n2 = 262144 / 4;
    // total = 1310720 = 1280 * 1024; +2 grid_build blocks
    prep_kernel<<<1282, 1024, 0, stream>>>(
        (const float4*)x, (ushort4*)xb, n0,
        (const float4*)w_qkv, (ushort4*)wqb, n1,
        (const float4*)w_proj, (ushort4*)wpb, n2,
        coords, gstart, sxy, sidx);

    knn_grid<<<2048, 256, 0, stream>>>(gstart, sxy, nn);
    gemm_bt<false, true><<<768, 256, 0, stream>>>(xb, wqb, qkv, 1536, 512,
                                                  nullptr, nullptr, sidx);
    attn_kernel<<<2048, 256, 0, stream>>>(qkv, nn, sidx, g);
    gemm_bt<true, false><<<256, 256, 0, stream>>>(g, wpb, out, 512, 512,
                                                  b_proj, x, nullptr);
}